// Round 1
// 642.747 us; speedup vs baseline: 1.0188x; 1.0188x over previous
//
#include <hip/hip_runtime.h>

#define FIN 256
#define FH  64
#define SCAN_BLK 1024
#define NCHUNK 8

// ---------------- degree ----------------

__global__ __launch_bounds__(256) void deg_kernel(const int* __restrict__ rows,
                                                  unsigned* __restrict__ deg, int E) {
    int e = blockIdx.x * 256 + threadIdx.x;
    if (e < E) atomicAdd(&deg[rows[e]], 1u);
}

// ---------------- scan: per-block scan of deg -> rowptr (block-local) + block totals ----------------

__global__ __launch_bounds__(256) void scan_block_kernel(const unsigned* __restrict__ deg,
                                                         int* __restrict__ rowptr,
                                                         int* __restrict__ blocksums, int N) {
    __shared__ int wsum[4];
    const int t = threadIdx.x;
    const int base = blockIdx.x * SCAN_BLK + t * 4;
    int d0 = 0, d1 = 0, d2 = 0, d3 = 0;
    if (base + 0 < N) d0 = (int)deg[base + 0];
    if (base + 1 < N) d1 = (int)deg[base + 1];
    if (base + 2 < N) d2 = (int)deg[base + 2];
    if (base + 3 < N) d3 = (int)deg[base + 3];
    const int tot = d0 + d1 + d2 + d3;
    const int lane = t & 63, wv = t >> 6;
    int inc = tot;
#pragma unroll
    for (int off = 1; off < 64; off <<= 1) {
        int v = __shfl_up(inc, off, 64);
        if (lane >= off) inc += v;
    }
    if (lane == 63) wsum[wv] = inc;
    __syncthreads();
    int woff = 0;
    for (int w = 0; w < wv; ++w) woff += wsum[w];
    const int ex = woff + inc - tot;   // exclusive prefix of this thread within block
    if (base + 0 < N) rowptr[base + 0] = ex;
    if (base + 1 < N) rowptr[base + 1] = ex + d0;
    if (base + 2 < N) rowptr[base + 2] = ex + d0 + d1;
    if (base + 3 < N) rowptr[base + 3] = ex + d0 + d1 + d2;
    if (t == 255) blocksums[blockIdx.x] = woff + inc;   // block TOTAL (unscanned)
}

// ---------------- scan_add: add cross-block prefix; also emit cursor and dis ----------------

__global__ __launch_bounds__(256) void scan_add_kernel(int* __restrict__ rowptr,
                                                       int* __restrict__ cursor,
                                                       const unsigned* __restrict__ deg,
                                                       float* __restrict__ dis,
                                                       const int* __restrict__ blocksums,
                                                       int nb, int N, int E) {
    __shared__ int pre;
    const int t = threadIdx.x;
    const int i0 = blockIdx.x * 256;
    const int c0 = i0 / SCAN_BLK;
    if (t == 0) {
        int s = 0;
        for (int k = 0; k < c0; ++k) s += blocksums[k];
        pre = s;
    }
    __syncthreads();
    int i = i0 + t;
    if (i < N) {
        int v = rowptr[i] + pre;
        rowptr[i] = v;
        cursor[i] = v;
        unsigned d = deg[i];
        dis[i] = d ? 1.0f / sqrtf((float)d) : 0.0f;
    }
    if (i == 0) rowptr[N] = E;
}

// ---------------- counting-sort edges into CSR col array, row-range chunked ----------------

__global__ __launch_bounds__(256) void scatter_edges_kernel(const int* __restrict__ rows,
                                                            const int* __restrict__ cols,
                                                            int* __restrict__ cursor,
                                                            int* __restrict__ colOut,
                                                            int* __restrict__ inv,
                                                            float chunk_scale, int E) {
    const int chunk = blockIdx.x & (NCHUNK - 1);
    const int eb = blockIdx.x >> 3;
    int e = eb * 256 + threadIdx.x;
    if (e >= E) return;
    int r = rows[e];
    int rc = (int)((float)r * chunk_scale);
    rc = rc > (NCHUNK - 1) ? (NCHUNK - 1) : rc;
    if (rc == chunk) {
        int p = atomicAdd(&cursor[r], 1);
        colOut[p] = cols[e];
        inv[e] = p;
    }
}

// ---------------- GEMM1: out[N][64] = (x[N][256] @ W[256][64] + b) * dis[r] ----------------

__global__ __launch_bounds__(256) void gemm1_kernel(const float* __restrict__ x,
                                                    const float* __restrict__ W,
                                                    const float* __restrict__ b,
                                                    const float* __restrict__ dis,
                                                    float* __restrict__ out, int N) {
    __shared__ float xs[32][132];
    __shared__ float ws[32][64];
    const int t = threadIdx.x;
    const int rb = blockIdx.x * 128;
    const int rg = t >> 3, cg = t & 7;
    const int r0 = rg * 4, c0 = cg * 8;
    float acc[4][8];
#pragma unroll
    for (int i = 0; i < 4; ++i)
#pragma unroll
        for (int j = 0; j < 8; ++j) acc[i][j] = 0.f;

    const float4* x4 = (const float4*)x;
    const int kk = (t & 7) * 4;
    const int rloc = t >> 3;

    for (int k0 = 0; k0 < FIN; k0 += 32) {
        __syncthreads();
        {
            const float4* w4 = (const float4*)(W + k0 * 64);
            float4* wl = (float4*)&ws[0][0];
            wl[t]       = w4[t];
            wl[t + 256] = w4[t + 256];
        }
#pragma unroll
        for (int p = 0; p < 4; ++p) {
            int r = rloc + p * 32;
            int gr = rb + r; if (gr >= N) gr = N - 1;
            float4 v = x4[gr * 64 + (k0 >> 2) + (t & 7)];
            xs[kk + 0][r] = v.x; xs[kk + 1][r] = v.y;
            xs[kk + 2][r] = v.z; xs[kk + 3][r] = v.w;
        }
        __syncthreads();
#pragma unroll
        for (int k = 0; k < 32; ++k) {
            float4 xa = *(const float4*)&xs[k][r0];
            float4 wa = *(const float4*)&ws[k][c0];
            float4 wb = *(const float4*)&ws[k][c0 + 4];
            float xr[4] = {xa.x, xa.y, xa.z, xa.w};
            float wr[8] = {wa.x, wa.y, wa.z, wa.w, wb.x, wb.y, wb.z, wb.w};
#pragma unroll
            for (int i = 0; i < 4; ++i)
#pragma unroll
                for (int j = 0; j < 8; ++j) acc[i][j] = fmaf(xr[i], wr[j], acc[i][j]);
        }
    }
    float bias[8];
#pragma unroll
    for (int j = 0; j < 8; ++j) bias[j] = b[c0 + j];
#pragma unroll
    for (int i = 0; i < 4; ++i) {
        int gr = rb + r0 + i;
        if (gr < N) {
            float d = dis[gr];
            float4 o0, o1;
            o0.x = (acc[i][0] + bias[0]) * d; o0.y = (acc[i][1] + bias[1]) * d;
            o0.z = (acc[i][2] + bias[2]) * d; o0.w = (acc[i][3] + bias[3]) * d;
            o1.x = (acc[i][4] + bias[4]) * d; o1.y = (acc[i][5] + bias[5]) * d;
            o1.z = (acc[i][6] + bias[6]) * d; o1.w = (acc[i][7] + bias[7]) * d;
            *(float4*)&out[gr * 64 + c0]     = o0;
            *(float4*)&out[gr * 64 + c0 + 4] = o1;
        }
    }
}

// ---------------- CSR gather aggregation (16-deep MLP) ----------------

__global__ __launch_bounds__(256) void gather_agg_kernel(const int* __restrict__ rowptr,
                                                         const int* __restrict__ cols,
                                                         const float* __restrict__ h,
                                                         const float* __restrict__ dscale,
                                                         float* __restrict__ out, int N) {
    int r = blockIdx.x * 4 + (threadIdx.x >> 6);
    int lane = threadIdx.x & 63;
    if (r >= N) return;
    int s = rowptr[r], e = rowptr[r + 1];
    float acc[8];
#pragma unroll
    for (int u = 0; u < 8; ++u) acc[u] = 0.f;
    for (int base = s; base < e; base += 64) {
        int n = e - base; if (n > 64) n = 64;
        int idx = (lane < n) ? cols[base + lane] : 0;
        int j = 0;
        for (; j + 15 < n; j += 16) {
            float tv[16];
#pragma unroll
            for (int u = 0; u < 16; ++u) {
                int c = __shfl(idx, j + u, 64);
                tv[u] = h[(size_t)c * 64 + lane];
            }
#pragma unroll
            for (int u = 0; u < 16; ++u) acc[u & 7] += tv[u];
        }
        for (; j + 3 < n; j += 4) {
            float tv[4];
#pragma unroll
            for (int u = 0; u < 4; ++u) {
                int c = __shfl(idx, j + u, 64);
                tv[u] = h[(size_t)c * 64 + lane];
            }
#pragma unroll
            for (int u = 0; u < 4; ++u) acc[u] += tv[u];
        }
        for (; j < n; ++j) {
            int c = __shfl(idx, j, 64);
            acc[0] += h[(size_t)c * 64 + lane];
        }
    }
    float v = ((acc[0] + acc[1]) + (acc[2] + acc[3])) + ((acc[4] + acc[5]) + (acc[6] + acc[7]));
    if (dscale) v *= dscale[r];
    out[(size_t)r * 64 + lane] = v;
}

// ---------------- GEMM2 ----------------

__global__ __launch_bounds__(256) void gemm2_kernel(const float* __restrict__ agg,
                                                    const float* __restrict__ dis,
                                                    const float* __restrict__ W,
                                                    const float* __restrict__ b,
                                                    float* __restrict__ out, int N) {
    __shared__ float xs[64][132];
    __shared__ float ws[64][64];
    const int t = threadIdx.x;
    const int rb = blockIdx.x * 128;
    {
        const float4* w4 = (const float4*)W;
        float4* wl = (float4*)&ws[0][0];
#pragma unroll
        for (int p = 0; p < 4; ++p) wl[p * 256 + t] = w4[p * 256 + t];
    }
    {
        const float4* a4 = (const float4*)agg;
        const int c4 = (t & 15) * 4;
        const int rloc = t >> 4;
#pragma unroll
        for (int p = 0; p < 8; ++p) {
            int r = rloc + p * 16;
            int gr = rb + r; if (gr >= N) gr = N - 1;
            float d = dis[gr];
            float4 v = a4[gr * 16 + (t & 15)];
            xs[c4 + 0][r] = fmaxf(v.x * d, 0.f);
            xs[c4 + 1][r] = fmaxf(v.y * d, 0.f);
            xs[c4 + 2][r] = fmaxf(v.z * d, 0.f);
            xs[c4 + 3][r] = fmaxf(v.w * d, 0.f);
        }
    }
    __syncthreads();
    const int rg = t >> 3, cg = t & 7;
    const int r0 = rg * 4, c0 = cg * 8;
    float acc[4][8];
#pragma unroll
    for (int i = 0; i < 4; ++i)
#pragma unroll
        for (int j = 0; j < 8; ++j) acc[i][j] = 0.f;
#pragma unroll 16
    for (int k = 0; k < 64; ++k) {
        float4 xa = *(const float4*)&xs[k][r0];
        float4 wa = *(const float4*)&ws[k][c0];
        float4 wb = *(const float4*)&ws[k][c0 + 4];
        float xr[4] = {xa.x, xa.y, xa.z, xa.w};
        float wr[8] = {wa.x, wa.y, wa.z, wa.w, wb.x, wb.y, wb.z, wb.w};
#pragma unroll
        for (int i = 0; i < 4; ++i)
#pragma unroll
            for (int j = 0; j < 8; ++j) acc[i][j] = fmaf(xr[i], wr[j], acc[i][j]);
    }
    float bias[8];
#pragma unroll
    for (int j = 0; j < 8; ++j) bias[j] = b[c0 + j];
#pragma unroll
    for (int i = 0; i < 4; ++i) {
        int gr = rb + r0 + i;
        if (gr < N) {
            float d = dis[gr];
            float4 o0, o1;
            o0.x = (acc[i][0] + bias[0]) * d; o0.y = (acc[i][1] + bias[1]) * d;
            o0.z = (acc[i][2] + bias[2]) * d; o0.w = (acc[i][3] + bias[3]) * d;
            o1.x = (acc[i][4] + bias[4]) * d; o1.y = (acc[i][5] + bias[5]) * d;
            o1.z = (acc[i][6] + bias[6]) * d; o1.w = (acc[i][7] + bias[7]) * d;
            *(float4*)&out[gr * 64 + c0]     = o0;
            *(float4*)&out[gr * 64 + c0 + 4] = o1;
        }
    }
}

// ---------------- pos decode via CSR: P[p] = dot64(z[a], z[colsorted[p]]) ----------------
// wave per row; z[a] in registers (replicated over four 16-lane groups);
// cols prefetched 64-wide, 16 neighbors per step -> 4 z4 loads in flight per thread.

__global__ __launch_bounds__(256) void decode_csr_kernel(const int* __restrict__ rowptr,
                                                         const int* __restrict__ cols,
                                                         const float* __restrict__ z,
                                                         float* __restrict__ P, int N) {
    int r = blockIdx.x * 4 + (threadIdx.x >> 6);
    int lane = threadIdx.x & 63;
    if (r >= N) return;
    int s = rowptr[r], e = rowptr[r + 1];
    if (s == e) return;
    const int l16 = lane & 15;
    const int grp = lane >> 4;   // 0..3
    const float4* z4 = (const float4*)z;
    const float4 zr = z4[(size_t)r * 16 + l16];
    for (int base = s; base < e; base += 64) {
        int n = e - base; if (n > 64) n = 64;
        int idx = (lane < n) ? cols[base + lane] : 0;
        for (int j = 0; j < n; j += 16) {
            int pos[4];
            bool act[4];
            float4 vb[4];
#pragma unroll
            for (int q = 0; q < 4; ++q) {
                pos[q] = j + q * 4 + grp;
                act[q] = pos[q] < n;
                int c = __shfl(idx, act[q] ? pos[q] : 0, 64);
                vb[q] = z4[(size_t)c * 16 + l16];
            }
#pragma unroll
            for (int q = 0; q < 4; ++q) {
                float p = zr.x * vb[q].x + zr.y * vb[q].y + zr.z * vb[q].z + zr.w * vb[q].w;
                p += __shfl_xor(p, 8);
                p += __shfl_xor(p, 4);
                p += __shfl_xor(p, 2);
                p += __shfl_xor(p, 1);
                if (act[q] && l16 == 0) P[base + pos[q]] = p;
            }
        }
    }
}

// ---------------- permute: out[e] = P[inv[e]] ----------------

__global__ __launch_bounds__(256) void permute_kernel(const float* __restrict__ P,
                                                      const int* __restrict__ inv,
                                                      float* __restrict__ out, int E) {
    int e = blockIdx.x * 256 + threadIdx.x;
    if (e < E) out[e] = P[inv[e]];
}

// ---------------- neg decode: out[Ep+j] = dot64(z[a], z[b]) ----------------
// 16 lanes per edge, 8 edges per group in flight (16 independent 256B loads).

__global__ __launch_bounds__(256) void decode_neg_kernel(const int* __restrict__ ne,
                                                         const float* __restrict__ z,
                                                         float* __restrict__ out, int En) {
    const int t = threadIdx.x;
    const int grp = t >> 4;      // 0..15
    const int l16 = t & 15;
    const int base = blockIdx.x * 128 + grp;
    const float4* z4 = (const float4*)z;

    int a[8], b[8];
    bool v[8];
#pragma unroll
    for (int q = 0; q < 8; ++q) {
        int e = base + q * 16;
        v[q] = e < En;
        a[q] = 0; b[q] = 0;
        if (v[q]) { a[q] = ne[e]; b[q] = ne[En + e]; }
    }
    float4 va[8], vb[8];
#pragma unroll
    for (int q = 0; q < 8; ++q) {
        va[q] = z4[(size_t)a[q] * 16 + l16];
        vb[q] = z4[(size_t)b[q] * 16 + l16];
    }
#pragma unroll
    for (int q = 0; q < 8; ++q) {
        float p = va[q].x * vb[q].x + va[q].y * vb[q].y
                + va[q].z * vb[q].z + va[q].w * vb[q].w;
        p += __shfl_xor(p, 8);
        p += __shfl_xor(p, 4);
        p += __shfl_xor(p, 2);
        p += __shfl_xor(p, 1);
        if (v[q] && l16 == 0) out[base + q * 16] = p;
    }
}

// ---------------- launch ----------------

extern "C" void kernel_launch(void* const* d_in, const int* in_sizes, int n_in,
                              void* d_out, int out_size, void* d_ws, size_t ws_size,
                              hipStream_t stream) {
    const float* x  = (const float*)d_in[0];
    const int*   pe = (const int*)d_in[1];
    const int*   ne = (const int*)d_in[2];
    const float* W1 = (const float*)d_in[3];
    const float* b1 = (const float*)d_in[4];
    const float* W2 = (const float*)d_in[5];
    const float* b2 = (const float*)d_in[6];
    float* outp = (float*)d_out;

    const int N  = in_sizes[0] / FIN;
    const int Ep = in_sizes[1] / 2;
    const int En = in_sizes[2] / 2;

    char* w = (char*)d_ws;
    size_t off = 0;
    auto alloc = [&](size_t bytes) {
        void* p = w + off;
        off = (off + bytes + 255) & ~(size_t)255;
        return p;
    };
    unsigned* deg   = (unsigned*)alloc((size_t)N * 4);
    float* dis      = (float*)alloc((size_t)N * 4);
    int* rowptr     = (int*)alloc((size_t)(N + 1) * 4);
    int* cursor     = (int*)alloc((size_t)N * 4);
    int* blocksums  = (int*)alloc(((size_t)N / SCAN_BLK + 2) * 4);
    int* colsorted  = (int*)alloc((size_t)Ep * 4);
    int* inv        = (int*)alloc((size_t)Ep * 4);
    float* A        = (float*)alloc((size_t)N * 64 * 4);   // h, then h2, then P (pos decode buf)
    float* B        = (float*)alloc((size_t)N * 64 * 4);   // agg1, then zfull

    const int nscan = (N + SCAN_BLK - 1) / SCAN_BLK;
    const int nEdgeBlocks = (Ep + 255) / 256;

    hipMemsetAsync(deg, 0, (size_t)N * 4, stream);

    // CSR build (pos edges)
    deg_kernel<<<nEdgeBlocks, 256, 0, stream>>>(pe, deg, Ep);
    scan_block_kernel<<<nscan, 256, 0, stream>>>(deg, rowptr, blocksums, N);
    scan_add_kernel<<<(N + 255) / 256, 256, 0, stream>>>(rowptr, cursor, deg, dis,
                                                         blocksums, nscan, N, Ep);
    scatter_edges_kernel<<<nEdgeBlocks * NCHUNK, 256, 0, stream>>>(
        pe, pe + Ep, cursor, colsorted, inv, (float)NCHUNK / (float)N, Ep);
    // layer 1
    gemm1_kernel<<<(N + 127) / 128, 256, 0, stream>>>(x, W1, b1, dis, A, N);
    gather_agg_kernel<<<(N + 3) / 4, 256, 0, stream>>>(rowptr, colsorted, A, nullptr, B, N);
    // layer 2
    gemm2_kernel<<<(N + 127) / 128, 256, 0, stream>>>(B, dis, W2, b2, A, N);
    gather_agg_kernel<<<(N + 3) / 4, 256, 0, stream>>>(rowptr, colsorted, A, dis, B, N);
    // decode: pos via CSR (z[a] in regs, sequential P write) + permute back; neg via gather
    float* P = A;   // h2 dead after gather2
    decode_csr_kernel<<<(N + 3) / 4, 256, 0, stream>>>(rowptr, colsorted, B, P, N);
    decode_neg_kernel<<<(En + 127) / 128, 256, 0, stream>>>(ne, B, outp + Ep, En);
    permute_kernel<<<(Ep + 255) / 256, 256, 0, stream>>>(P, inv, outp, Ep);
}